// Round 1
// baseline (733.519 us; speedup 1.0000x reference)
//
#include <hip/hip_runtime.h>
#include <math.h>

#define BZd 16
#define INd 512
#define Sd  512
#define Od  512
#define Ld  2048
#define CLd 128
#define NCd (Ld / CLd)   // 16 chunks

// -------------------- A_diag = -softplus(A_unc) --------------------
__global__ void prep_adiag(const float* __restrict__ A_unc, float* __restrict__ A_diag) {
    int s = threadIdx.x;
    if (s < Sd) {
        float x = A_unc[s];
        float sp = fmaxf(x, 0.0f) + log1pf(expf(-fabsf(x)));
        A_diag[s] = -sp;
    }
}

// -------------------- Bu GEMM: xbuf[b][l][s] = sum_i u[b][i][l] * B[s][i] ----
// M = l (2048), N = s (512), K = i (512). 64x64 tile, TK=16, 256 threads, 4x4 micro.
__global__ __launch_bounds__(256) void gemm_bu(const float* __restrict__ u,
                                               const float* __restrict__ Bm,
                                               float* __restrict__ xbuf) {
    __shared__ float As[16][64];  // [k][m=l]
    __shared__ float Bs[16][64];  // [k][n=s]
    int b  = blockIdx.z;
    int l0 = blockIdx.y * 64;
    int n0 = blockIdx.x * 64;
    int tid = threadIdx.x;
    int tx = tid & 15, ty = tid >> 4;
    float acc[4][4] = {};
    const float* ub = u + (size_t)b * INd * Ld;

    for (int k0 = 0; k0 < INd; k0 += 16) {
        {   // A tile: As[kk][mm] = u[b][k0+kk][l0+mm]  (contiguous in l -> direct)
            int kk = tid >> 4;   // 0..15
            int m4 = tid & 15;   // 0..15
            float4 v = *(const float4*)&ub[(size_t)(k0 + kk) * Ld + l0 + m4 * 4];
            *(float4*)&As[kk][m4 * 4] = v;
        }
        {   // B tile: Bs[kk][nn] = B[n0+nn][k0+kk]  (contiguous in i -> transpose store)
            int nn = tid >> 2;   // 0..63
            int k4 = tid & 3;    // 0..3
            float4 v = *(const float4*)&Bm[(size_t)(n0 + nn) * INd + k0 + k4 * 4];
            Bs[k4 * 4 + 0][nn] = v.x;
            Bs[k4 * 4 + 1][nn] = v.y;
            Bs[k4 * 4 + 2][nn] = v.z;
            Bs[k4 * 4 + 3][nn] = v.w;
        }
        __syncthreads();
        #pragma unroll
        for (int kk = 0; kk < 16; ++kk) {
            float4 a4 = *(const float4*)&As[kk][ty * 4];
            float4 b4 = *(const float4*)&Bs[kk][tx * 4];
            float av[4] = {a4.x, a4.y, a4.z, a4.w};
            float bv[4] = {b4.x, b4.y, b4.z, b4.w};
            #pragma unroll
            for (int i = 0; i < 4; ++i)
                #pragma unroll
                for (int j = 0; j < 4; ++j)
                    acc[i][j] = fmaf(av[i], bv[j], acc[i][j]);
        }
        __syncthreads();
    }
    float* xb = xbuf + (size_t)b * Ld * Sd;
    #pragma unroll
    for (int i = 0; i < 4; ++i) {
        float4 v = {acc[i][0], acc[i][1], acc[i][2], acc[i][3]};
        *(float4*)&xb[(size_t)(l0 + ty * 4 + i) * Sd + n0 + tx * 4] = v;
    }
}

// -------------------- scan pass A: per-chunk local end value --------------------
// thread = (b, c, s); ce[b,c,s] = local scan (zero-init) end of chunk c
__global__ __launch_bounds__(256) void pass_ce(const float* __restrict__ xbuf,
                                               const float* __restrict__ A_diag,
                                               float* __restrict__ ce) {
    int g = blockIdx.x * 256 + threadIdx.x;
    int s = g & (Sd - 1);
    int c = (g >> 9) & (NCd - 1);
    int b = g >> 13;
    float a = A_diag[s];
    const float* p = xbuf + ((size_t)b * Ld + (size_t)c * CLd) * Sd + s;
    float x = 0.0f;
    #pragma unroll 4
    for (int j = 0; j < CLd; ++j)
        x = fmaf(a, x, p[(size_t)j * Sd]);
    ce[((size_t)b * NCd + c) * Sd + s] = x;
}

// -------------------- scan pass B: sequential carry across chunks ---------------
// thread = (b, s); cin[b,c,s] = state entering chunk c
__global__ __launch_bounds__(256) void pass_carry(const float* __restrict__ ce,
                                                  const float* __restrict__ A_diag,
                                                  const float* __restrict__ h0,
                                                  float* __restrict__ cin) {
    int g = blockIdx.x * 256 + threadIdx.x;
    int s = g & (Sd - 1);
    int b = g >> 9;
    float a = A_diag[s];
    float aCL = a;
    #pragma unroll
    for (int i = 0; i < 7; ++i) aCL *= aCL;   // a^128
    float carry = h0[s];
    for (int c = 0; c < NCd; ++c) {
        size_t idx = ((size_t)b * NCd + c) * Sd + s;
        cin[idx] = carry;
        carry = fmaf(aCL, carry, ce[idx]);
    }
}

// -------------------- scan pass C: full scan with correct chunk init, in place ---
__global__ __launch_bounds__(256) void pass_scan(float* __restrict__ xbuf,
                                                 const float* __restrict__ A_diag,
                                                 const float* __restrict__ cin) {
    int g = blockIdx.x * 256 + threadIdx.x;
    int s = g & (Sd - 1);
    int c = (g >> 9) & (NCd - 1);
    int b = g >> 13;
    float a = A_diag[s];
    float x = cin[((size_t)b * NCd + c) * Sd + s];
    float* p = xbuf + ((size_t)b * Ld + (size_t)c * CLd) * Sd + s;
    #pragma unroll 4
    for (int j = 0; j < CLd; ++j) {
        float v = p[(size_t)j * Sd];
        x = fmaf(a, x, v);
        p[(size_t)j * Sd] = x;
    }
}

// -------------------- Y GEMM: Y[b][o][l] = sum_s C[o][s]*xs[b][l][s] + sum_i D[o][i]*u[b][i][l]
// M = o (512), N = l (2048). Two K phases accumulate into same acc.
__global__ __launch_bounds__(256) void gemm_y(const float* __restrict__ xbuf,
                                              const float* __restrict__ u,
                                              const float* __restrict__ Cm,
                                              const float* __restrict__ Dm,
                                              float* __restrict__ Y) {
    __shared__ float As[16][64];  // [k][m=o]
    __shared__ float Bs[16][64];  // [k][n=l]
    int b  = blockIdx.z;
    int m0 = blockIdx.y * 64;
    int n0 = blockIdx.x * 64;
    int tid = threadIdx.x;
    int tx = tid & 15, ty = tid >> 4;
    float acc[4][4] = {};
    const float* xb = xbuf + (size_t)b * Ld * Sd;
    const float* ub = u + (size_t)b * INd * Ld;

    // phase 1: K over STATE_DIM; A = C (row-major [m][k]), Bop[n][k] = xs[b][l][s]
    for (int k0 = 0; k0 < Sd; k0 += 16) {
        {
            int mm = tid >> 2, k4 = tid & 3;
            float4 v = *(const float4*)&Cm[(size_t)(m0 + mm) * Sd + k0 + k4 * 4];
            As[k4 * 4 + 0][mm] = v.x;
            As[k4 * 4 + 1][mm] = v.y;
            As[k4 * 4 + 2][mm] = v.z;
            As[k4 * 4 + 3][mm] = v.w;
        }
        {
            int nn = tid >> 2, k4 = tid & 3;
            float4 v = *(const float4*)&xb[(size_t)(n0 + nn) * Sd + k0 + k4 * 4];
            Bs[k4 * 4 + 0][nn] = v.x;
            Bs[k4 * 4 + 1][nn] = v.y;
            Bs[k4 * 4 + 2][nn] = v.z;
            Bs[k4 * 4 + 3][nn] = v.w;
        }
        __syncthreads();
        #pragma unroll
        for (int kk = 0; kk < 16; ++kk) {
            float4 a4 = *(const float4*)&As[kk][ty * 4];
            float4 b4 = *(const float4*)&Bs[kk][tx * 4];
            float av[4] = {a4.x, a4.y, a4.z, a4.w};
            float bv[4] = {b4.x, b4.y, b4.z, b4.w};
            #pragma unroll
            for (int i = 0; i < 4; ++i)
                #pragma unroll
                for (int j = 0; j < 4; ++j)
                    acc[i][j] = fmaf(av[i], bv[j], acc[i][j]);
        }
        __syncthreads();
    }

    // phase 2: K over IN_DIM; A = D (row-major), Bop[k][n] = u[b][i][l] (direct)
    for (int k0 = 0; k0 < INd; k0 += 16) {
        {
            int mm = tid >> 2, k4 = tid & 3;
            float4 v = *(const float4*)&Dm[(size_t)(m0 + mm) * INd + k0 + k4 * 4];
            As[k4 * 4 + 0][mm] = v.x;
            As[k4 * 4 + 1][mm] = v.y;
            As[k4 * 4 + 2][mm] = v.z;
            As[k4 * 4 + 3][mm] = v.w;
        }
        {
            int kk = tid >> 4, n4 = tid & 15;
            float4 v = *(const float4*)&ub[(size_t)(k0 + kk) * Ld + n0 + n4 * 4];
            *(float4*)&Bs[kk][n4 * 4] = v;
        }
        __syncthreads();
        #pragma unroll
        for (int kk = 0; kk < 16; ++kk) {
            float4 a4 = *(const float4*)&As[kk][ty * 4];
            float4 b4 = *(const float4*)&Bs[kk][tx * 4];
            float av[4] = {a4.x, a4.y, a4.z, a4.w};
            float bv[4] = {b4.x, b4.y, b4.z, b4.w};
            #pragma unroll
            for (int i = 0; i < 4; ++i)
                #pragma unroll
                for (int j = 0; j < 4; ++j)
                    acc[i][j] = fmaf(av[i], bv[j], acc[i][j]);
        }
        __syncthreads();
    }

    #pragma unroll
    for (int i = 0; i < 4; ++i) {
        float4 v = {acc[i][0], acc[i][1], acc[i][2], acc[i][3]};
        *(float4*)&Y[((size_t)b * Od + m0 + ty * 4 + i) * Ld + n0 + tx * 4] = v;
    }
}

extern "C" void kernel_launch(void* const* d_in, const int* in_sizes, int n_in,
                              void* d_out, int out_size, void* d_ws, size_t ws_size,
                              hipStream_t stream) {
    const float* u  = (const float*)d_in[0];
    const float* Au = (const float*)d_in[1];
    const float* Bm = (const float*)d_in[2];
    const float* Cm = (const float*)d_in[3];
    const float* Dm = (const float*)d_in[4];
    const float* h0 = (const float*)d_in[5];
    float* Y = (float*)d_out;

    char* ws = (char*)d_ws;
    float* xbuf   = (float*)ws;                                  // 16*2048*512*4 = 64 MiB
    float* A_diag = (float*)(ws + (size_t)BZd * Ld * Sd * 4);    // 2 KiB
    float* ce     = A_diag + Sd;                                 // 512 KiB
    float* cin    = ce + (size_t)BZd * NCd * Sd;                 // 512 KiB

    prep_adiag<<<1, 512, 0, stream>>>(Au, A_diag);
    gemm_bu<<<dim3(Sd / 64, Ld / 64, BZd), 256, 0, stream>>>(u, Bm, xbuf);
    pass_ce<<<(BZd * NCd * Sd) / 256, 256, 0, stream>>>(xbuf, A_diag, ce);
    pass_carry<<<(BZd * Sd) / 256, 256, 0, stream>>>(ce, A_diag, h0, cin);
    pass_scan<<<(BZd * NCd * Sd) / 256, 256, 0, stream>>>(xbuf, A_diag, cin);
    gemm_y<<<dim3(Ld / 64, Od / 64, BZd), 256, 0, stream>>>(xbuf, u, Cm, Dm, Y);
}

// Round 2
// 118.935 us; speedup vs baseline: 6.1674x; 6.1674x over previous
//
#include <hip/hip_runtime.h>
#include <math.h>

typedef __bf16 bf16;
typedef __bf16 bf16x8 __attribute__((ext_vector_type(8)));
typedef __bf16 bf16x4 __attribute__((ext_vector_type(4)));
typedef float  f32x4  __attribute__((ext_vector_type(4)));

#define BZd 16
#define INd 512
#define Sd  512
#define Od  512
#define Ld  2048
#define Kd  512
#define CLd 128
#define NCd (Ld / CLd)   // 16 chunks

// -------------------- A_diag = -softplus(A_unc) --------------------
__global__ void prep_adiag(const float* __restrict__ A_unc, float* __restrict__ A_diag) {
    int s = threadIdx.x;
    if (s < Sd) {
        float x = A_unc[s];
        float sp = fmaxf(x, 0.0f) + log1pf(expf(-fabsf(x)));
        A_diag[s] = -sp;
    }
}

// -------------------- convert B, C, D (f32 -> bf16) --------------------
__global__ __launch_bounds__(256) void conv_w3(const float* __restrict__ B,
                                               const float* __restrict__ C,
                                               const float* __restrict__ D,
                                               bf16* __restrict__ Bb,
                                               bf16* __restrict__ Cb,
                                               bf16* __restrict__ Db) {
    int bid = blockIdx.x;
    int which = bid >> 8;          // 0..2 (256 blocks per matrix)
    int lb = bid & 255;
    const float* s = which == 0 ? B : (which == 1 ? C : D);
    bf16* d = which == 0 ? Bb : (which == 1 ? Cb : Db);
    int i = lb * 256 + threadIdx.x;         // i indexes float4 groups
    float4 v = *(const float4*)&s[(size_t)i * 4];
    bf16x4 o = { (bf16)v.x, (bf16)v.y, (bf16)v.z, (bf16)v.w };
    *(bf16x4*)&d[(size_t)i * 4] = o;
}

// -------------------- transpose+convert u: [b][i][l] f32 -> u_t[b][l][i] bf16 ----
__global__ __launch_bounds__(256) void transp_u(const float* __restrict__ u,
                                                bf16* __restrict__ ut) {
    __shared__ bf16 t[64][73];   // [i][l], pad 73 to spread banks
    int b = blockIdx.z, i0 = blockIdx.y * 64, l0 = blockIdx.x * 64;
    int tid = threadIdx.x, tx = tid & 15, ty = tid >> 4;
    const float* ub = u + ((size_t)b * INd + i0) * Ld + l0;
    #pragma unroll
    for (int r = 0; r < 4; ++r) {
        int il = r * 16 + ty;
        float4 v = *(const float4*)&ub[(size_t)il * Ld + tx * 4];
        t[il][tx * 4 + 0] = (bf16)v.x;
        t[il][tx * 4 + 1] = (bf16)v.y;
        t[il][tx * 4 + 2] = (bf16)v.z;
        t[il][tx * 4 + 3] = (bf16)v.w;
    }
    __syncthreads();
    bf16* uo = ut + ((size_t)b * Ld + l0) * INd + i0;
    #pragma unroll
    for (int it = 0; it < 2; ++it) {
        int q = it * 256 + tid;
        int lr = q >> 3;          // 0..63 (l within tile)
        int ic = (q & 7) * 8;     // i-chunk base
        bf16x8 o;
        #pragma unroll
        for (int e = 0; e < 8; ++e) o[e] = t[ic + e][lr];
        *(bf16x8*)&uo[(size_t)lr * INd + ic] = o;
    }
}

// -------------------- 128x128 MFMA GEMM (bf16 in, f32 acc) --------------------
// A: [M][K] k-contig (row stride Kd). B: [N][K] k-contig. Out[M][N].
// NPH phases accumulate into the same acc (used for Y = C*xs + D*u).
// Staging: global_load_lds w=16, linear LDS + source-chunk-XOR-swizzle,
// reads swizzled back (T2 involution). 4 waves, 64x64 per wave.
template<int NPH, bool OBF16>
__global__ __launch_bounds__(256) void gemm128(
    const bf16* __restrict__ A0, unsigned aBS0,
    const bf16* __restrict__ B0, unsigned bBS0,
    const bf16* __restrict__ A1, unsigned aBS1,
    const bf16* __restrict__ B1, unsigned bBS1,
    void* __restrict__ OutV, unsigned long oBS, int ldOut,
    int NX, int NY)
{
    __shared__ bf16 As[128 * 64];
    __shared__ bf16 Bs[128 * 64];
    int tid = threadIdx.x;
    int lw = tid & 63, w = tid >> 6;

    // bijective XCD swizzle (gridDim.x % 8 == 0)
    int nwg = gridDim.x;
    int bid = blockIdx.x;
    int cpx = nwg >> 3;
    int swz = (bid & 7) * cpx + (bid >> 3);
    int pb = NX * NY;
    int b  = swz / pb;
    int rr0 = swz - b * pb;
    int by = rr0 / NX;
    int bx = rr0 - by * NX;

    int wm = w >> 1, wn = w & 1;
    int fr = lw & 15, g = lw >> 4;

    f32x4 acc[4][4];
    #pragma unroll
    for (int i = 0; i < 4; ++i)
        #pragma unroll
        for (int j = 0; j < 4; ++j)
            acc[i][j] = (f32x4){0.f, 0.f, 0.f, 0.f};

    int rowStage = w * 8 + (lw >> 3);   // + rr*32 -> tile row
    int chunkLane = lw & 7;

    #pragma unroll
    for (int ph = 0; ph < NPH; ++ph) {
        const bf16* Ap = (ph == 0 ? A0 + (size_t)b * aBS0 : A1 + (size_t)b * aBS1)
                         + (size_t)(by * 128) * Kd;
        const bf16* Bp = (ph == 0 ? B0 + (size_t)b * bBS0 : B1 + (size_t)b * bBS1)
                         + (size_t)(bx * 128) * Kd;
        for (int k0 = 0; k0 < Kd; k0 += 64) {
            #pragma unroll
            for (int rr = 0; rr < 4; ++rr) {
                int row = rr * 32 + rowStage;
                int cs = chunkLane ^ (row & 7);   // pre-swizzled global source chunk
                __builtin_amdgcn_global_load_lds(
                    (const __attribute__((address_space(1))) void*)(Ap + (size_t)row * Kd + k0 + cs * 8),
                    (__attribute__((address_space(3))) void*)&As[(rr * 32 + w * 8) * 64],
                    16, 0, 0);
                __builtin_amdgcn_global_load_lds(
                    (const __attribute__((address_space(1))) void*)(Bp + (size_t)row * Kd + k0 + cs * 8),
                    (__attribute__((address_space(3))) void*)&Bs[(rr * 32 + w * 8) * 64],
                    16, 0, 0);
            }
            __syncthreads();
            bf16x8 af[4][2], bfr[4][2];
            #pragma unroll
            for (int i = 0; i < 4; ++i) {
                int rowA = wm * 64 + i * 16 + fr;
                int rowB = wn * 64 + i * 16 + fr;
                #pragma unroll
                for (int p = 0; p < 2; ++p) {
                    int ca = ((p << 2) | g) ^ (rowA & 7);   // swizzled read chunk
                    int cb = ((p << 2) | g) ^ (rowB & 7);
                    af[i][p]  = *(const bf16x8*)&As[rowA * 64 + ca * 8];
                    bfr[i][p] = *(const bf16x8*)&Bs[rowB * 64 + cb * 8];
                }
            }
            #pragma unroll
            for (int p = 0; p < 2; ++p)
                #pragma unroll
                for (int i = 0; i < 4; ++i)
                    #pragma unroll
                    for (int j = 0; j < 4; ++j)
                        acc[i][j] = __builtin_amdgcn_mfma_f32_16x16x32_bf16(
                            af[i][p], bfr[j][p], acc[i][j], 0, 0, 0);
            __syncthreads();
        }
    }

    // epilogue: C/D layout col=lane&15, row=(lane>>4)*4+reg
    int m0 = by * 128 + wm * 64 + g * 4;
    int n0 = bx * 128 + wn * 64 + fr;
    if (OBF16) {
        bf16* out = (bf16*)OutV + (size_t)b * oBS;
        #pragma unroll
        for (int i = 0; i < 4; ++i)
            #pragma unroll
            for (int j = 0; j < 4; ++j)
                #pragma unroll
                for (int q = 0; q < 4; ++q)
                    out[(size_t)(m0 + i * 16 + q) * ldOut + n0 + j * 16] = (bf16)acc[i][j][q];
    } else {
        float* out = (float*)OutV + (size_t)b * oBS;
        #pragma unroll
        for (int i = 0; i < 4; ++i)
            #pragma unroll
            for (int j = 0; j < 4; ++j)
                #pragma unroll
                for (int q = 0; q < 4; ++q)
                    out[(size_t)(m0 + i * 16 + q) * ldOut + n0 + j * 16] = acc[i][j][q];
    }
}

// -------------------- scan pass A: per-chunk local end value --------------------
__global__ __launch_bounds__(256) void pass_ce(const bf16* __restrict__ xbuf,
                                               const float* __restrict__ A_diag,
                                               float* __restrict__ ce) {
    int gI = blockIdx.x * 256 + threadIdx.x;
    int s = gI & (Sd - 1);
    int c = (gI >> 9) & (NCd - 1);
    int b = gI >> 13;
    float a = A_diag[s];
    const bf16* p = xbuf + ((size_t)b * Ld + (size_t)c * CLd) * Sd + s;
    float x = 0.0f;
    #pragma unroll 4
    for (int j = 0; j < CLd; ++j)
        x = fmaf(a, x, (float)p[(size_t)j * Sd]);
    ce[((size_t)b * NCd + c) * Sd + s] = x;
}

// -------------------- scan pass B: sequential carry across chunks ---------------
__global__ __launch_bounds__(256) void pass_carry(const float* __restrict__ ce,
                                                  const float* __restrict__ A_diag,
                                                  const float* __restrict__ h0,
                                                  float* __restrict__ cin) {
    int gI = blockIdx.x * 256 + threadIdx.x;
    int s = gI & (Sd - 1);
    int b = gI >> 9;
    float a = A_diag[s];
    float aCL = a;
    #pragma unroll
    for (int i = 0; i < 7; ++i) aCL *= aCL;   // a^128
    float carry = h0[s];
    for (int c = 0; c < NCd; ++c) {
        size_t idx = ((size_t)b * NCd + c) * Sd + s;
        cin[idx] = carry;
        carry = fmaf(aCL, carry, ce[idx]);
    }
}

// -------------------- scan pass C: full scan in place (bf16 out) ---------------
__global__ __launch_bounds__(256) void pass_scan(bf16* __restrict__ xbuf,
                                                 const float* __restrict__ A_diag,
                                                 const float* __restrict__ cin) {
    int gI = blockIdx.x * 256 + threadIdx.x;
    int s = gI & (Sd - 1);
    int c = (gI >> 9) & (NCd - 1);
    int b = gI >> 13;
    float a = A_diag[s];
    float x = cin[((size_t)b * NCd + c) * Sd + s];
    bf16* p = xbuf + ((size_t)b * Ld + (size_t)c * CLd) * Sd + s;
    #pragma unroll 4
    for (int j = 0; j < CLd; ++j) {
        float v = (float)p[(size_t)j * Sd];
        x = fmaf(a, x, v);
        p[(size_t)j * Sd] = (bf16)x;
    }
}

extern "C" void kernel_launch(void* const* d_in, const int* in_sizes, int n_in,
                              void* d_out, int out_size, void* d_ws, size_t ws_size,
                              hipStream_t stream) {
    const float* u  = (const float*)d_in[0];
    const float* Au = (const float*)d_in[1];
    const float* Bm = (const float*)d_in[2];
    const float* Cm = (const float*)d_in[3];
    const float* Dm = (const float*)d_in[4];
    const float* h0 = (const float*)d_in[5];
    float* Y = (float*)d_out;

    char* ws = (char*)d_ws;
    bf16* bu = (bf16*)ws;                            // 32 MiB, becomes xs after scan
    bf16* ut = (bf16*)(ws + (32ull << 20));          // 32 MiB
    bf16* Bb = (bf16*)(ws + (64ull << 20));          // 512 KiB
    bf16* Cb = Bb + 262144;
    bf16* Db = Cb + 262144;
    float* A_diag = (float*)(ws + (64ull << 20) + 3ull * 524288);
    float* ce  = A_diag + 512;                       // 512 KiB
    float* cin = ce + (size_t)BZd * NCd * Sd;        // 512 KiB

    conv_w3<<<768, 256, 0, stream>>>(Bm, Cm, Dm, Bb, Cb, Db);
    prep_adiag<<<1, 512, 0, stream>>>(Au, A_diag);
    transp_u<<<dim3(Ld / 64, INd / 64, BZd), 256, 0, stream>>>(u, ut);

    // gemm_bu: M=l(2048), N=s(512), K=i(512); A=u_t (batched), B=B_bf (shared)
    gemm128<1, true><<<(Sd / 128) * (Ld / 128) * BZd, 256, 0, stream>>>(
        ut, (unsigned)(Ld * INd), Bb, 0u,
        ut, 0u, Bb, 0u,
        (void*)bu, (unsigned long)(Ld * Sd), Sd,
        Sd / 128, Ld / 128);

    pass_ce<<<(BZd * NCd * Sd) / 256, 256, 0, stream>>>(bu, A_diag, ce);
    pass_carry<<<(BZd * Sd) / 256, 256, 0, stream>>>(ce, A_diag, h0, cin);
    pass_scan<<<(BZd * NCd * Sd) / 256, 256, 0, stream>>>(bu, A_diag, cin);

    // gemm_y: M=o(512), N=l(2048); phase0 A=C,B=xs(batched); phase1 A=D,B=u_t(batched)
    gemm128<2, false><<<(Ld / 128) * (Od / 128) * BZd, 256, 0, stream>>>(
        Cb, 0u, bu, (unsigned)(Ld * Sd),
        Db, 0u, ut, (unsigned)(Ld * INd),
        (void*)Y, (unsigned long)(Od * Ld), Ld,
        Ld / 128, Od / 128);
}

// Round 3
// 118.091 us; speedup vs baseline: 6.2115x; 1.0071x over previous
//
#include <hip/hip_runtime.h>
#include <math.h>

typedef __bf16 bf16;
typedef __bf16 bf16x8 __attribute__((ext_vector_type(8)));
typedef __bf16 bf16x4 __attribute__((ext_vector_type(4)));
typedef float  f32x4  __attribute__((ext_vector_type(4)));

#define BZd 16
#define INd 512
#define Sd  512
#define Od  512
#define Ld  2048
#define Kd  512
#define CLd 128
#define NCd (Ld / CLd)   // 16 chunks

// -------------------- A_diag = -softplus(A_unc) --------------------
__global__ void prep_adiag(const float* __restrict__ A_unc, float* __restrict__ A_diag) {
    int s = threadIdx.x;
    if (s < Sd) {
        float x = A_unc[s];
        float sp = fmaxf(x, 0.0f) + log1pf(expf(-fabsf(x)));
        A_diag[s] = -sp;
    }
}

// -------------------- convert B, C, D (f32 -> bf16) --------------------
__global__ __launch_bounds__(256) void conv_w3(const float* __restrict__ B,
                                               const float* __restrict__ C,
                                               const float* __restrict__ D,
                                               bf16* __restrict__ Bb,
                                               bf16* __restrict__ Cb,
                                               bf16* __restrict__ Db) {
    int bid = blockIdx.x;
    int which = bid >> 8;
    int lb = bid & 255;
    const float* s = which == 0 ? B : (which == 1 ? C : D);
    bf16* d = which == 0 ? Bb : (which == 1 ? Cb : Db);
    int i = lb * 256 + threadIdx.x;
    float4 v = *(const float4*)&s[(size_t)i * 4];
    bf16x4 o = { (bf16)v.x, (bf16)v.y, (bf16)v.z, (bf16)v.w };
    *(bf16x4*)&d[(size_t)i * 4] = o;
}

// -------------------- transpose+convert u: [b][i][l] f32 -> u_t[b][l][i] bf16 ----
__global__ __launch_bounds__(256) void transp_u(const float* __restrict__ u,
                                                bf16* __restrict__ ut) {
    __shared__ bf16 t[64][73];
    int b = blockIdx.z, i0 = blockIdx.y * 64, l0 = blockIdx.x * 64;
    int tid = threadIdx.x, tx = tid & 15, ty = tid >> 4;
    const float* ub = u + ((size_t)b * INd + i0) * Ld + l0;
    #pragma unroll
    for (int r = 0; r < 4; ++r) {
        int il = r * 16 + ty;
        float4 v = *(const float4*)&ub[(size_t)il * Ld + tx * 4];
        t[il][tx * 4 + 0] = (bf16)v.x;
        t[il][tx * 4 + 1] = (bf16)v.y;
        t[il][tx * 4 + 2] = (bf16)v.z;
        t[il][tx * 4 + 3] = (bf16)v.w;
    }
    __syncthreads();
    bf16* uo = ut + ((size_t)b * Ld + l0) * INd + i0;
    #pragma unroll
    for (int it = 0; it < 2; ++it) {
        int q = it * 256 + tid;
        int lr = q >> 3;
        int ic = (q & 7) * 8;
        bf16x8 o;
        #pragma unroll
        for (int e = 0; e < 8; ++e) o[e] = t[ic + e][lr];
        *(bf16x8*)&uo[(size_t)lr * INd + ic] = o;
    }
}

// -------------------- 256x256 MFMA GEMM, BK=32, tri-buffered, counted vmcnt ----
// A: [M][K] k-contig. B: [N][K] k-contig. Out[M][N]. NT K-tiles of 32
// (NT==32 -> two operand phases of 16 tiles each, accumulating).
// 8 waves (2M x 4N), per-wave output 128x64. One s_barrier per tile,
// steady-state s_waitcnt vmcnt(4) (stage runs 2 tiles ahead, 3 LDS buffers).
template<int NT, bool OBF16>
__global__ __launch_bounds__(512, 2) void gemm256(
    const bf16* __restrict__ A0, size_t aBS0,
    const bf16* __restrict__ B0, size_t bBS0,
    const bf16* __restrict__ A1, size_t aBS1,
    const bf16* __restrict__ B1, size_t bBS1,
    void* __restrict__ OutV, size_t oBS, int ldOut,
    int NX, int NY)
{
    __shared__ bf16 lds[3 * 16384];   // 3 bufs x (A 256x32 + B 256x32) bf16 = 96 KiB
    const int tid  = threadIdx.x;
    const int lane = tid & 63, w = tid >> 6;

    // bijective XCD swizzle (gridDim.x % 8 == 0)
    int nwg = gridDim.x, bid = blockIdx.x;
    int cpx = nwg >> 3;
    int swz = (bid & 7) * cpx + (bid >> 3);
    int pb = NX * NY;
    int b  = swz / pb;
    int r0 = swz - b * pb;
    int by = r0 / NX;
    int bx = r0 - by * NX;

    const int wm = w >> 2, wn = w & 3;       // 2 x 4 wave grid
    const int fr = lane & 15, g = lane >> 4;

    const bf16* Abase0 = A0 + (size_t)b * aBS0 + (size_t)(by * 256) * Kd;
    const bf16* Bbase0 = B0 + (size_t)b * bBS0 + (size_t)(bx * 256) * Kd;
    const bf16* Abase1 = (NT == 32) ? (A1 + (size_t)b * aBS1 + (size_t)(by * 256) * Kd) : Abase0;
    const bf16* Bbase1 = (NT == 32) ? (B1 + (size_t)b * bBS1 + (size_t)(bx * 256) * Kd) : Bbase0;

    f32x4 acc[8][4];
    #pragma unroll
    for (int i = 0; i < 8; ++i)
        #pragma unroll
        for (int j = 0; j < 4; ++j)
            acc[i][j] = (f32x4){0.f, 0.f, 0.f, 0.f};

    // ---- staging: per thread 2 x 16B chunk-loads per matrix per tile ----
    auto stage = [&](int t) {
        bf16* dst = &lds[(t % 3) * 16384];
        const bf16* Ap;
        const bf16* Bp;
        if (NT == 32 && t >= 16) {
            Ap = Abase1 + (t - 16) * 32;
            Bp = Bbase1 + (t - 16) * 32;
        } else {
            Ap = Abase0 + t * 32;
            Bp = Bbase0 + t * 32;
        }
        #pragma unroll
        for (int e = 0; e < 2; ++e) {
            int blk = w * 2 + e;                 // wave-uniform
            int q   = blk * 64 + lane;           // 16B-chunk index 0..1023
            int row = q >> 2;
            int key = (row & 3) ^ ((row >> 2) & 3);
            int csrc = (q & 3) ^ key;            // pre-swizzled source chunk
            __builtin_amdgcn_global_load_lds(
                (const __attribute__((address_space(1))) void*)(Ap + (size_t)row * Kd + csrc * 8),
                (__attribute__((address_space(3))) void*)(dst + blk * 512),
                16, 0, 0);
            __builtin_amdgcn_global_load_lds(
                (const __attribute__((address_space(1))) void*)(Bp + (size_t)row * Kd + csrc * 8),
                (__attribute__((address_space(3))) void*)(dst + 8192 + blk * 512),
                16, 0, 0);
        }
    };

    // ---- compute one K-tile: 12 ds_read_b128 + 32 MFMA per wave ----
    auto compute = [&](int t) {
        const bf16* As_ = &lds[(t % 3) * 16384];
        const bf16* Bs_ = As_ + 8192;
        bf16x8 bv[4];
        #pragma unroll
        for (int j = 0; j < 4; ++j) {
            int row = wn * 64 + j * 16 + fr;
            int c = g ^ (row & 3) ^ ((row >> 2) & 3);
            bv[j] = *(const bf16x8*)&Bs_[row * 32 + c * 8];
        }
        #pragma unroll
        for (int h = 0; h < 2; ++h) {
            bf16x8 av[4];
            #pragma unroll
            for (int i = 0; i < 4; ++i) {
                int row = wm * 128 + (h * 4 + i) * 16 + fr;
                int c = g ^ (row & 3) ^ ((row >> 2) & 3);
                av[i] = *(const bf16x8*)&As_[row * 32 + c * 8];
            }
            __builtin_amdgcn_s_setprio(1);
            #pragma unroll
            for (int i = 0; i < 4; ++i)
                #pragma unroll
                for (int j = 0; j < 4; ++j)
                    acc[h * 4 + i][j] = __builtin_amdgcn_mfma_f32_16x16x32_bf16(
                        av[i], bv[j], acc[h * 4 + i][j], 0, 0, 0);
            __builtin_amdgcn_s_setprio(0);
        }
    };

    // ---- pipeline ----
    stage(0);
    stage(1);                                    // 8 loads in flight
    for (int t = 0; t < NT - 2; ++t) {
        asm volatile("s_waitcnt vmcnt(4)" ::: "memory");   // tile t landed
        __builtin_amdgcn_sched_barrier(0);
        __builtin_amdgcn_s_barrier();
        __builtin_amdgcn_sched_barrier(0);
        stage(t + 2);                            // into buffer freed at t-1
        compute(t);
    }
    asm volatile("s_waitcnt vmcnt(4)" ::: "memory");
    __builtin_amdgcn_sched_barrier(0);
    __builtin_amdgcn_s_barrier();
    __builtin_amdgcn_sched_barrier(0);
    compute(NT - 2);
    asm volatile("s_waitcnt vmcnt(0)" ::: "memory");
    __builtin_amdgcn_sched_barrier(0);
    __builtin_amdgcn_s_barrier();
    __builtin_amdgcn_sched_barrier(0);
    compute(NT - 1);

    // ---- epilogue: C/D layout col=lane&15, row=(lane>>4)*4+reg ----
    int m0 = by * 256 + wm * 128 + g * 4;
    int n0 = bx * 256 + wn * 64 + fr;
    if (OBF16) {
        bf16* out = (bf16*)OutV + (size_t)b * oBS;
        #pragma unroll
        for (int i = 0; i < 8; ++i)
            #pragma unroll
            for (int j = 0; j < 4; ++j)
                #pragma unroll
                for (int q = 0; q < 4; ++q)
                    out[(size_t)(m0 + i * 16 + q) * ldOut + n0 + j * 16] = (bf16)acc[i][j][q];
    } else {
        float* out = (float*)OutV + (size_t)b * oBS;
        #pragma unroll
        for (int i = 0; i < 8; ++i)
            #pragma unroll
            for (int j = 0; j < 4; ++j)
                #pragma unroll
                for (int q = 0; q < 4; ++q)
                    out[(size_t)(m0 + i * 16 + q) * ldOut + n0 + j * 16] = acc[i][j][q];
    }
}

// -------------------- scan pass A: per-chunk local end value --------------------
__global__ __launch_bounds__(256) void pass_ce(const bf16* __restrict__ xbuf,
                                               const float* __restrict__ A_diag,
                                               float* __restrict__ ce) {
    int gI = blockIdx.x * 256 + threadIdx.x;
    int s = gI & (Sd - 1);
    int c = (gI >> 9) & (NCd - 1);
    int b = gI >> 13;
    float a = A_diag[s];
    const bf16* p = xbuf + ((size_t)b * Ld + (size_t)c * CLd) * Sd + s;
    float x = 0.0f;
    #pragma unroll 4
    for (int j = 0; j < CLd; ++j)
        x = fmaf(a, x, (float)p[(size_t)j * Sd]);
    ce[((size_t)b * NCd + c) * Sd + s] = x;
}

// -------------------- scan pass B: sequential carry across chunks ---------------
__global__ __launch_bounds__(256) void pass_carry(const float* __restrict__ ce,
                                                  const float* __restrict__ A_diag,
                                                  const float* __restrict__ h0,
                                                  float* __restrict__ cin) {
    int gI = blockIdx.x * 256 + threadIdx.x;
    int s = gI & (Sd - 1);
    int b = gI >> 9;
    float a = A_diag[s];
    float aCL = a;
    #pragma unroll
    for (int i = 0; i < 7; ++i) aCL *= aCL;   // a^128
    float carry = h0[s];
    for (int c = 0; c < NCd; ++c) {
        size_t idx = ((size_t)b * NCd + c) * Sd + s;
        cin[idx] = carry;
        carry = fmaf(aCL, carry, ce[idx]);
    }
}

// -------------------- scan pass C: full scan in place (bf16 out) ---------------
__global__ __launch_bounds__(256) void pass_scan(bf16* __restrict__ xbuf,
                                                 const float* __restrict__ A_diag,
                                                 const float* __restrict__ cin) {
    int gI = blockIdx.x * 256 + threadIdx.x;
    int s = gI & (Sd - 1);
    int c = (gI >> 9) & (NCd - 1);
    int b = gI >> 13;
    float a = A_diag[s];
    float x = cin[((size_t)b * NCd + c) * Sd + s];
    bf16* p = xbuf + ((size_t)b * Ld + (size_t)c * CLd) * Sd + s;
    #pragma unroll 4
    for (int j = 0; j < CLd; ++j) {
        float v = (float)p[(size_t)j * Sd];
        x = fmaf(a, x, v);
        p[(size_t)j * Sd] = (bf16)x;
    }
}

extern "C" void kernel_launch(void* const* d_in, const int* in_sizes, int n_in,
                              void* d_out, int out_size, void* d_ws, size_t ws_size,
                              hipStream_t stream) {
    const float* u  = (const float*)d_in[0];
    const float* Au = (const float*)d_in[1];
    const float* Bm = (const float*)d_in[2];
    const float* Cm = (const float*)d_in[3];
    const float* Dm = (const float*)d_in[4];
    const float* h0 = (const float*)d_in[5];
    float* Y = (float*)d_out;

    char* ws = (char*)d_ws;
    bf16* bu = (bf16*)ws;                            // 32 MiB, becomes xs after scan
    bf16* ut = (bf16*)(ws + (32ull << 20));          // 32 MiB
    bf16* Bb = (bf16*)(ws + (64ull << 20));          // 512 KiB
    bf16* Cb = Bb + 262144;
    bf16* Db = Cb + 262144;
    float* A_diag = (float*)(ws + (64ull << 20) + 3ull * 524288);
    float* ce  = A_diag + 512;
    float* cin = ce + (size_t)BZd * NCd * Sd;

    conv_w3<<<768, 256, 0, stream>>>(Bm, Cm, Dm, Bb, Cb, Db);
    prep_adiag<<<1, 512, 0, stream>>>(Au, A_diag);
    transp_u<<<dim3(Ld / 64, INd / 64, BZd), 256, 0, stream>>>(u, ut);

    // gemm_bu: M=l(2048), N=s(512), K=i(512); A=u_t (batched), B=B_bf (shared)
    gemm256<16, true><<<(Sd / 256) * (Ld / 256) * BZd, 512, 0, stream>>>(
        ut, (size_t)Ld * INd, Bb, 0,
        ut, 0, Bb, 0,
        (void*)bu, (size_t)Ld * Sd, Sd,
        Sd / 256, Ld / 256);

    pass_ce<<<(BZd * NCd * Sd) / 256, 256, 0, stream>>>(bu, A_diag, ce);
    pass_carry<<<(BZd * Sd) / 256, 256, 0, stream>>>(ce, A_diag, h0, cin);
    pass_scan<<<(BZd * NCd * Sd) / 256, 256, 0, stream>>>(bu, A_diag, cin);

    // gemm_y: M=o(512), N=l(2048); phase0 A=C,B=xs(batched); phase1 A=D,B=u_t(batched)
    gemm256<32, false><<<(Ld / 256) * (Od / 256) * BZd, 512, 0, stream>>>(
        Cb, 0, bu, (size_t)Ld * Sd,
        Db, 0, ut, (size_t)Ld * INd,
        (void*)Y, (size_t)Od * Ld, Ld,
        Ld / 256, Od / 256);
}

// Round 4
// 108.115 us; speedup vs baseline: 6.7846x; 1.0923x over previous
//
#include <hip/hip_runtime.h>
#include <math.h>

typedef __bf16 bf16;
typedef __bf16 bf16x2 __attribute__((ext_vector_type(2)));
typedef __bf16 bf16x4 __attribute__((ext_vector_type(4)));
typedef __bf16 bf16x8 __attribute__((ext_vector_type(8)));
typedef float  f32x4  __attribute__((ext_vector_type(4)));

#define BZd 16
#define INd 512
#define Sd  512
#define Od  512
#define Ld  2048
#define CLd 128
#define NCd (Ld / CLd)   // 16 chunks

// ---- prep_all: blocks 0-255 conv B, 256-511 conv C, 512-767 conv D (+flag), 768 A_diag
__global__ __launch_bounds__(256) void prep_all(const float* __restrict__ B,
                                                const float* __restrict__ C,
                                                const float* __restrict__ D,
                                                const float* __restrict__ Au,
                                                bf16* __restrict__ Bb, bf16* __restrict__ Cb,
                                                bf16* __restrict__ Db, float* __restrict__ A_diag,
                                                int* __restrict__ dflag) {
    int bid = blockIdx.x;
    if (bid == 768) {
        #pragma unroll
        for (int r = 0; r < 2; ++r) {
            int ss = threadIdx.x + r * 256;
            float x = Au[ss];
            float sp = fmaxf(x, 0.0f) + log1pf(expf(-fabsf(x)));
            A_diag[ss] = -sp;
        }
        return;
    }
    int which = bid >> 8, lb = bid & 255;
    const float* src = which == 0 ? B : (which == 1 ? C : D);
    bf16* dst = which == 0 ? Bb : (which == 1 ? Cb : Db);
    int i = lb * 256 + threadIdx.x;
    float4 v = *(const float4*)&src[(size_t)i * 4];
    bf16x4 o = { (bf16)v.x, (bf16)v.y, (bf16)v.z, (bf16)v.w };
    *(bf16x4*)&dst[(size_t)i * 4] = o;
    if (which == 2) {
        bool nz = (v.x != 0.f) | (v.y != 0.f) | (v.z != 0.f) | (v.w != 0.f);
        unsigned long long bl = __ballot(nz);
        if (bl && ((threadIdx.x & 63) == 0)) atomicOr(dflag, 1);
    }
}

// ---- transpose+convert u: [b][i][l] f32 -> u_t[b][l][i] bf16
__global__ __launch_bounds__(256) void transp_u(const float* __restrict__ u,
                                                bf16* __restrict__ ut) {
    __shared__ bf16 t[64][73];
    int b = blockIdx.z, i0 = blockIdx.y * 64, l0 = blockIdx.x * 64;
    int tid = threadIdx.x, tx = tid & 15, ty = tid >> 4;
    const float* ub = u + ((size_t)b * INd + i0) * Ld + l0;
    #pragma unroll
    for (int r = 0; r < 4; ++r) {
        int il = r * 16 + ty;
        float4 v = *(const float4*)&ub[(size_t)il * Ld + tx * 4];
        t[il][tx * 4 + 0] = (bf16)v.x;
        t[il][tx * 4 + 1] = (bf16)v.y;
        t[il][tx * 4 + 2] = (bf16)v.z;
        t[il][tx * 4 + 3] = (bf16)v.w;
    }
    __syncthreads();
    bf16* uo = ut + ((size_t)b * Ld + l0) * INd + i0;
    #pragma unroll
    for (int it = 0; it < 2; ++it) {
        int q = it * 256 + tid;
        int lr = q >> 3;
        int ic = (q & 7) * 8;
        bf16x8 o;
        #pragma unroll
        for (int e = 0; e < 8; ++e) o[e] = t[ic + e][lr];
        *(bf16x8*)&uo[(size_t)lr * INd + ic] = o;
    }
}

// ---- 256x256 MFMA GEMM, BK=64 split in K-half units, 8-phase counted-vmcnt pipeline.
// A: [M][K=512/set] k-contig stride 512. B: [N][K] k-contig stride 512. Out[M][N].
// Unit U = (tile T=U>>1, k-half kh=U&1) = A(256x32)+B(256x32) = 32KiB = 1 LDS slot (of 4).
// Stage unit U+3 (2 instrs/phase) while consuming U; gate vmcnt(8) once per unit.
// 8 waves (2M x 4N), per-wave out 128x64; per phase: 16 MFMA (m-half x all n x one k-half).
template<bool OBF16>
__global__ __launch_bounds__(512, 2) void gemm8p(
    const bf16* __restrict__ A0, size_t aBS0,
    const bf16* __restrict__ B0, size_t bBS0,
    const bf16* __restrict__ A1, size_t aBS1,
    const bf16* __restrict__ B1, size_t bBS1,
    const int* __restrict__ dfp,
    void* __restrict__ OutV, size_t oBS, int ldOut,
    int NX, int NY)
{
    __shared__ bf16 lds[4 * 16384];   // 4 slots x 32KiB = 128 KiB
    const int tid = threadIdx.x;
    const int lane = tid & 63, w = tid >> 6;

    int nwg = gridDim.x, bid = blockIdx.x;
    int cpx = nwg >> 3;
    int swz = (bid & 7) * cpx + (bid >> 3);
    int pb = NX * NY;
    int b  = swz / pb;
    int r0 = swz - b * pb;
    int by = r0 / NX;
    int bx = r0 - by * NX;

    const int wm = w >> 2, wn = w & 3;
    const int fr = lane & 15, g = lane >> 4;

    int extra = dfp ? *dfp : 0;
    const int NT = extra ? 16 : 8;
    const int NU = 2 * NT;

    const bf16* Ab0 = A0 + (size_t)b * aBS0 + (size_t)(by * 256) * 512;
    const bf16* Bb0 = B0 + (size_t)b * bBS0 + (size_t)(bx * 256) * 512;
    const bf16* Ab1 = A1 + (size_t)b * aBS1 + (size_t)(by * 256) * 512;
    const bf16* Bb1 = B1 + (size_t)b * bBS1 + (size_t)(bx * 256) * 512;

    f32x4 acc[8][4];
    #pragma unroll
    for (int i = 0; i < 8; ++i)
        #pragma unroll
        for (int j = 0; j < 4; ++j)
            acc[i][j] = (f32x4){0.f, 0.f, 0.f, 0.f};

    // stage one matrix (A or B) k-half of unit U: 2 x global_load_lds(16B)/thread
    auto stage_part = [&](int U, int isB) {
        int T = U >> 1, kh = U & 1;
        const bf16* Mb = isB ? (T >= 8 ? Bb1 : Bb0) : (T >= 8 ? Ab1 : Ab0);
        int kbase = ((T & 7) << 6) + (kh << 5);
        int slot = U & 3;
        #pragma unroll
        for (int rblk = 0; rblk < 2; ++rblk) {
            int row = rblk * 128 + (tid >> 2);
            int pos = tid & 3;
            int cs = pos ^ ((row & 3) ^ ((row >> 2) & 3));
            __builtin_amdgcn_global_load_lds(
                (const __attribute__((address_space(1))) void*)(Mb + (size_t)row * 512 + kbase + cs * 8),
                (__attribute__((address_space(3))) void*)&lds[slot * 16384 + isB * 8192 + (rblk * 128 + w * 16) * 32],
                16, 0, 0);
        }
    };

    // prologue: units 0,1,2 (12 load-instrs in flight)
    stage_part(0, 0); stage_part(0, 1);
    stage_part(1, 0); stage_part(1, 1);
    stage_part(2, 0); stage_part(2, 1);

    bf16x8 av[4], bv[4];
    for (int U = 0; U < NU; ++U) {
        int ahead = NU - 1 - U;
        if (ahead >= 2)      { asm volatile("s_waitcnt vmcnt(8)" ::: "memory"); }
        else if (ahead == 1) { asm volatile("s_waitcnt vmcnt(4)" ::: "memory"); }
        else                 { asm volatile("s_waitcnt vmcnt(0)" ::: "memory"); }
        __builtin_amdgcn_sched_barrier(0);
        __builtin_amdgcn_s_barrier();
        __builtin_amdgcn_sched_barrier(0);

        const bf16* Ls = &lds[(U & 3) * 16384];
        #pragma unroll
        for (int mf = 0; mf < 2; ++mf) {
            if (mf == 1) {
                __builtin_amdgcn_sched_barrier(0);
                __builtin_amdgcn_s_barrier();
                __builtin_amdgcn_sched_barrier(0);
            }
            if (mf == 0) {
                #pragma unroll
                for (int j = 0; j < 4; ++j) {
                    int R = wn * 64 + j * 16 + fr;
                    int pos = g ^ ((R & 3) ^ ((R >> 2) & 3));
                    bv[j] = *(const bf16x8*)&Ls[8192 + R * 32 + pos * 8];
                }
            }
            #pragma unroll
            for (int i = 0; i < 4; ++i) {
                int R = wm * 128 + (mf * 4 + i) * 16 + fr;
                int pos = g ^ ((R & 3) ^ ((R >> 2) & 3));
                av[i] = *(const bf16x8*)&Ls[R * 32 + pos * 8];
            }
            if (U + 3 < NU) stage_part(U + 3, mf);
            asm volatile("s_waitcnt lgkmcnt(0)" ::: "memory");
            __builtin_amdgcn_sched_barrier(0);
            __builtin_amdgcn_s_setprio(1);
            #pragma unroll
            for (int i = 0; i < 4; ++i)
                #pragma unroll
                for (int j = 0; j < 4; ++j)
                    acc[mf * 4 + i][j] = __builtin_amdgcn_mfma_f32_16x16x32_bf16(
                        av[i], bv[j], acc[mf * 4 + i][j], 0, 0, 0);
            __builtin_amdgcn_s_setprio(0);
        }
    }

    // epilogue: C/D layout col=lane&15, row=(lane>>4)*4+reg
    int m0 = by * 256 + wm * 128 + g * 4;
    int n0 = bx * 256 + wn * 64 + fr;
    if (OBF16) {
        bf16* out = (bf16*)OutV + (size_t)b * oBS;
        #pragma unroll
        for (int i = 0; i < 8; ++i)
            #pragma unroll
            for (int j = 0; j < 4; ++j)
                #pragma unroll
                for (int q = 0; q < 4; ++q)
                    out[(size_t)(m0 + i * 16 + q) * ldOut + n0 + j * 16] = (bf16)acc[i][j][q];
    } else {
        float* out = (float*)OutV + (size_t)b * oBS;
        #pragma unroll
        for (int i = 0; i < 8; ++i)
            #pragma unroll
            for (int j = 0; j < 4; ++j)
                #pragma unroll
                for (int q = 0; q < 4; ++q)
                    out[(size_t)(m0 + i * 16 + q) * ldOut + n0 + j * 16] = acc[i][j][q];
    }
}

// ---- scan pass A: per-chunk local end value (2 states/thread, bf16x2 loads)
__global__ __launch_bounds__(256) void pass_ce2(const bf16* __restrict__ xbuf,
                                                const float* __restrict__ A_diag,
                                                float* __restrict__ ce) {
    int gI = blockIdx.x * 256 + threadIdx.x;
    int sp = gI & 255;
    int c = (gI >> 8) & (NCd - 1);
    int b = gI >> 12;
    int s = sp * 2;
    float a0 = A_diag[s], a1 = A_diag[s + 1];
    const bf16* p = xbuf + ((size_t)b * Ld + (size_t)c * CLd) * Sd + s;
    float x0 = 0.f, x1 = 0.f;
    #pragma unroll 4
    for (int j = 0; j < CLd; ++j) {
        bf16x2 v = *(const bf16x2*)&p[(size_t)j * Sd];
        x0 = fmaf(a0, x0, (float)v[0]);
        x1 = fmaf(a1, x1, (float)v[1]);
    }
    float2 o = { x0, x1 };
    *(float2*)&ce[((size_t)b * NCd + c) * Sd + s] = o;
}

// ---- scan pass B: carry (redone per block from ce) + full in-place scan, bf16x2
__global__ __launch_bounds__(256) void pass_scan2(bf16* __restrict__ xbuf,
                                                  const float* __restrict__ A_diag,
                                                  const float* __restrict__ ce,
                                                  const float* __restrict__ h0) {
    int gI = blockIdx.x * 256 + threadIdx.x;
    int sp = gI & 255;
    int c = (gI >> 8) & (NCd - 1);
    int b = gI >> 12;
    int s = sp * 2;
    float a0 = A_diag[s], a1 = A_diag[s + 1];
    float acl0 = a0, acl1 = a1;
    #pragma unroll
    for (int i = 0; i < 7; ++i) { acl0 *= acl0; acl1 *= acl1; }   // a^128
    float x0 = h0[s], x1 = h0[s + 1];
    for (int cp = 0; cp < NCd; ++cp) {
        if (cp >= c) break;
        float2 e = *(const float2*)&ce[((size_t)b * NCd + cp) * Sd + s];
        x0 = fmaf(acl0, x0, e.x);
        x1 = fmaf(acl1, x1, e.y);
    }
    bf16* p = xbuf + ((size_t)b * Ld + (size_t)c * CLd) * Sd + s;
    #pragma unroll 4
    for (int j = 0; j < CLd; ++j) {
        bf16x2 v = *(const bf16x2*)&p[(size_t)j * Sd];
        x0 = fmaf(a0, x0, (float)v[0]);
        x1 = fmaf(a1, x1, (float)v[1]);
        bf16x2 o = { (bf16)x0, (bf16)x1 };
        *(bf16x2*)&p[(size_t)j * Sd] = o;
    }
}

extern "C" void kernel_launch(void* const* d_in, const int* in_sizes, int n_in,
                              void* d_out, int out_size, void* d_ws, size_t ws_size,
                              hipStream_t stream) {
    const float* u  = (const float*)d_in[0];
    const float* Au = (const float*)d_in[1];
    const float* Bm = (const float*)d_in[2];
    const float* Cm = (const float*)d_in[3];
    const float* Dm = (const float*)d_in[4];
    const float* h0 = (const float*)d_in[5];
    float* Y = (float*)d_out;

    char* ws = (char*)d_ws;
    bf16* bu = (bf16*)ws;                            // 32 MiB, becomes xs after scan
    bf16* ut = (bf16*)(ws + (32ull << 20));          // 32 MiB
    bf16* Bb = (bf16*)(ws + (64ull << 20));          // 512 KiB each
    bf16* Cb = Bb + 262144;
    bf16* Db = Cb + 262144;
    float* A_diag = (float*)(ws + (64ull << 20) + 3ull * 524288);
    float* ce   = A_diag + 512;                      // 512 KiB
    int*   flag = (int*)(ce + (size_t)BZd * NCd * Sd);

    hipMemsetAsync(flag, 0, sizeof(int), stream);
    prep_all<<<769, 256, 0, stream>>>(Bm, Cm, Dm, Au, Bb, Cb, Db, A_diag, flag);
    transp_u<<<dim3(Ld / 64, INd / 64, BZd), 256, 0, stream>>>(u, ut);

    // gemm_bu: M=l(2048), N=s(512); A=u_t (batched), B=B_bf (shared); out bu bf16
    gemm8p<true><<<(Sd / 256) * (Ld / 256) * BZd, 512, 0, stream>>>(
        ut, (size_t)Ld * INd, Bb, 0,
        ut, (size_t)Ld * INd, Bb, 0,
        nullptr,
        (void*)bu, (size_t)Ld * Sd, Sd,
        Sd / 256, Ld / 256);

    pass_ce2<<<(BZd * NCd * (Sd / 2)) / 256, 256, 0, stream>>>(bu, A_diag, ce);
    pass_scan2<<<(BZd * NCd * (Sd / 2)) / 256, 256, 0, stream>>>(bu, A_diag, ce, h0);

    // gemm_y: M=o(512), N=l(2048); set0 A=C,B=xs; set1 (iff D!=0) A=D,B=u_t; out Y f32
    gemm8p<false><<<(Ld / 256) * (Od / 256) * BZd, 512, 0, stream>>>(
        Cb, 0, bu, (size_t)Ld * Sd,
        Db, 0, ut, (size_t)Ld * INd,
        flag,
        (void*)Y, (size_t)Od * Ld, Ld,
        Ld / 256, Od / 256);
}

// Round 5
// 97.248 us; speedup vs baseline: 7.5427x; 1.1117x over previous
//
#include <hip/hip_runtime.h>
#include <math.h>

typedef __bf16 bf16;
typedef __bf16 bf16x2 __attribute__((ext_vector_type(2)));
typedef __bf16 bf16x4 __attribute__((ext_vector_type(4)));
typedef __bf16 bf16x8 __attribute__((ext_vector_type(8)));
typedef float  f32x4  __attribute__((ext_vector_type(4)));

#define BZd 16
#define INd 512
#define Sd  512
#define Od  512
#define Ld  2048
#define CLd 128
#define NCd (Ld / CLd)   // 16 chunks

// ---- prep_all: blocks 0-255 conv B, 256-511 conv C, 512-767 conv D (+flag), 768 A_diag
__global__ __launch_bounds__(256) void prep_all(const float* __restrict__ B,
                                                const float* __restrict__ C,
                                                const float* __restrict__ D,
                                                const float* __restrict__ Au,
                                                bf16* __restrict__ Bb, bf16* __restrict__ Cb,
                                                bf16* __restrict__ Db, float* __restrict__ A_diag,
                                                int* __restrict__ dfa) {
    __shared__ int sred[4];
    int bid = blockIdx.x;
    if (bid == 768) {
        #pragma unroll
        for (int r = 0; r < 2; ++r) {
            int ss = threadIdx.x + r * 256;
            float x = Au[ss];
            float sp = fmaxf(x, 0.0f) + log1pf(expf(-fabsf(x)));
            A_diag[ss] = -sp;
        }
        return;
    }
    int which = bid >> 8, lb = bid & 255;
    const float* src = which == 0 ? B : (which == 1 ? C : D);
    bf16* dst = which == 0 ? Bb : (which == 1 ? Cb : Db);
    int i = lb * 256 + threadIdx.x;
    float4 v = *(const float4*)&src[(size_t)i * 4];
    bf16x4 o = { (bf16)v.x, (bf16)v.y, (bf16)v.z, (bf16)v.w };
    *(bf16x4*)&dst[(size_t)i * 4] = o;
    if (which == 2) {
        // block-level OR of "any nonzero in D", written unconditionally (no init needed)
        int nz = (v.x != 0.f) | (v.y != 0.f) | (v.z != 0.f) | (v.w != 0.f);
        unsigned long long bl = __ballot(nz);
        int wv = threadIdx.x >> 6;
        if ((threadIdx.x & 63) == 0) sred[wv] = (bl != 0ull);
        __syncthreads();
        if (threadIdx.x == 0) dfa[lb] = sred[0] | sred[1] | sred[2] | sred[3];
    }
}

// ---- transpose+convert u: [b][i][l] f32 -> u_t[b][l][i] bf16
__global__ __launch_bounds__(256) void transp_u(const float* __restrict__ u,
                                                bf16* __restrict__ ut) {
    __shared__ bf16 t[64][73];
    int b = blockIdx.z, i0 = blockIdx.y * 64, l0 = blockIdx.x * 64;
    int tid = threadIdx.x, tx = tid & 15, ty = tid >> 4;
    const float* ub = u + ((size_t)b * INd + i0) * Ld + l0;
    #pragma unroll
    for (int r = 0; r < 4; ++r) {
        int il = r * 16 + ty;
        float4 v = *(const float4*)&ub[(size_t)il * Ld + tx * 4];
        t[il][tx * 4 + 0] = (bf16)v.x;
        t[il][tx * 4 + 1] = (bf16)v.y;
        t[il][tx * 4 + 2] = (bf16)v.z;
        t[il][tx * 4 + 3] = (bf16)v.w;
    }
    __syncthreads();
    bf16* uo = ut + ((size_t)b * Ld + l0) * INd + i0;
    #pragma unroll
    for (int it = 0; it < 2; ++it) {
        int q = it * 256 + tid;
        int lr = q >> 3;
        int ic = (q & 7) * 8;
        bf16x8 o;
        #pragma unroll
        for (int e = 0; e < 8; ++e) o[e] = t[ic + e][lr];
        *(bf16x8*)&uo[(size_t)lr * INd + ic] = o;
    }
}

// ---- 256x256 MFMA GEMM, BK=64 split in K-half units, 8-phase counted-vmcnt pipeline.
// When CE (gemm_bu): epilogue computes per-chunk zero-init scan-end vectors into cePtr
// (wave's 128-row output block == exactly one scan chunk).
template<bool OBF16>
__global__ __launch_bounds__(512, 2) void gemm8p(
    const bf16* __restrict__ A0, size_t aBS0,
    const bf16* __restrict__ B0, size_t bBS0,
    const bf16* __restrict__ A1, size_t aBS1,
    const bf16* __restrict__ B1, size_t bBS1,
    const int* __restrict__ dfa,
    const float* __restrict__ A_diag, float* __restrict__ cePtr,
    void* __restrict__ OutV, size_t oBS, int ldOut,
    int NX, int NY)
{
    __shared__ bf16 lds[4 * 16384];   // 4 slots x 32KiB = 128 KiB
    const int tid = threadIdx.x;
    const int lane = tid & 63, w = tid >> 6;

    int nwg = gridDim.x, bid = blockIdx.x;
    int cpx = nwg >> 3;
    int swz = (bid & 7) * cpx + (bid >> 3);
    int pb = NX * NY;
    int b  = swz / pb;
    int r0 = swz - b * pb;
    int by = r0 / NX;
    int bx = r0 - by * NX;

    const int wm = w >> 2, wn = w & 3;
    const int fr = lane & 15, g = lane >> 4;

    int extra = 0;
    if (dfa) {
        int4 f = ((const int4*)dfa)[lane];
        extra = __any((f.x | f.y | f.z | f.w) != 0) ? 1 : 0;
    }
    const int NT = extra ? 16 : 8;
    const int NU = 2 * NT;

    const bf16* Ab0 = A0 + (size_t)b * aBS0 + (size_t)(by * 256) * 512;
    const bf16* Bb0 = B0 + (size_t)b * bBS0 + (size_t)(bx * 256) * 512;
    const bf16* Ab1 = A1 + (size_t)b * aBS1 + (size_t)(by * 256) * 512;
    const bf16* Bb1 = B1 + (size_t)b * bBS1 + (size_t)(bx * 256) * 512;

    f32x4 acc[8][4];
    #pragma unroll
    for (int i = 0; i < 8; ++i)
        #pragma unroll
        for (int j = 0; j < 4; ++j)
            acc[i][j] = (f32x4){0.f, 0.f, 0.f, 0.f};

    // stage one matrix (A or B) k-half of unit U: 2 x global_load_lds(16B)/thread
    auto stage_part = [&](int U, int isB) {
        int T = U >> 1, kh = U & 1;
        const bf16* Mb = isB ? (T >= 8 ? Bb1 : Bb0) : (T >= 8 ? Ab1 : Ab0);
        int kbase = ((T & 7) << 6) + (kh << 5);
        int slot = U & 3;
        #pragma unroll
        for (int rblk = 0; rblk < 2; ++rblk) {
            int row = rblk * 128 + (tid >> 2);
            int pos = tid & 3;
            int cs = pos ^ ((row & 3) ^ ((row >> 2) & 3));
            __builtin_amdgcn_global_load_lds(
                (const __attribute__((address_space(1))) void*)(Mb + (size_t)row * 512 + kbase + cs * 8),
                (__attribute__((address_space(3))) void*)&lds[slot * 16384 + isB * 8192 + (rblk * 128 + w * 16) * 32],
                16, 0, 0);
        }
    };

    // prologue: units 0,1,2 (12 load-instrs in flight)
    stage_part(0, 0); stage_part(0, 1);
    stage_part(1, 0); stage_part(1, 1);
    stage_part(2, 0); stage_part(2, 1);

    bf16x8 av[4], bv[4];
    for (int U = 0; U < NU; ++U) {
        int ahead = NU - 1 - U;
        if (ahead >= 2)      { asm volatile("s_waitcnt vmcnt(8)" ::: "memory"); }
        else if (ahead == 1) { asm volatile("s_waitcnt vmcnt(4)" ::: "memory"); }
        else                 { asm volatile("s_waitcnt vmcnt(0)" ::: "memory"); }
        __builtin_amdgcn_sched_barrier(0);
        __builtin_amdgcn_s_barrier();
        __builtin_amdgcn_sched_barrier(0);

        const bf16* Ls = &lds[(U & 3) * 16384];
        #pragma unroll
        for (int mf = 0; mf < 2; ++mf) {
            if (mf == 1) {
                __builtin_amdgcn_sched_barrier(0);
                __builtin_amdgcn_s_barrier();
                __builtin_amdgcn_sched_barrier(0);
            }
            if (mf == 0) {
                #pragma unroll
                for (int j = 0; j < 4; ++j) {
                    int R = wn * 64 + j * 16 + fr;
                    int pos = g ^ ((R & 3) ^ ((R >> 2) & 3));
                    bv[j] = *(const bf16x8*)&Ls[8192 + R * 32 + pos * 8];
                }
            }
            #pragma unroll
            for (int i = 0; i < 4; ++i) {
                int R = wm * 128 + (mf * 4 + i) * 16 + fr;
                int pos = g ^ ((R & 3) ^ ((R >> 2) & 3));
                av[i] = *(const bf16x8*)&Ls[R * 32 + pos * 8];
            }
            if (U + 3 < NU) stage_part(U + 3, mf);
            asm volatile("s_waitcnt lgkmcnt(0)" ::: "memory");
            __builtin_amdgcn_sched_barrier(0);
            __builtin_amdgcn_s_setprio(1);
            #pragma unroll
            for (int i = 0; i < 4; ++i)
                #pragma unroll
                for (int j = 0; j < 4; ++j)
                    acc[mf * 4 + i][j] = __builtin_amdgcn_mfma_f32_16x16x32_bf16(
                        av[i], bv[j], acc[mf * 4 + i][j], 0, 0, 0);
            __builtin_amdgcn_s_setprio(0);
        }
    }

    // ---- fused chunk-end scan (gemm_bu only): wave rows wm*128..+128 == chunk by*2+wm
    if (OBF16 && cePtr) {
        int colBase = bx * 256 + wn * 64;
        #pragma unroll
        for (int j = 0; j < 4; ++j) {
            float a = A_diag[colBase + j * 16 + fr];
            float a2 = a * a, a4 = a2 * a2, a8 = a4 * a4, a16 = a8 * a8;
            float S = 0.f;
            #pragma unroll
            for (int I = 0; I < 8; ++I) {
                f32x4 v = acc[I][j];
                // zero-init scan end over this lane's 4 consecutive rows (g*4+q)
                float e = fmaf(fmaf(fmaf(v[0], a, v[1]), a, v[2]), a, v[3]);
                float e0 = __shfl(e, fr);
                float e1 = __shfl(e, fr + 16);
                float e2 = __shfl(e, fr + 32);
                float e3 = __shfl(e, fr + 48);
                float E = fmaf(fmaf(fmaf(e0, a4, e1), a4, e2), a4, e3);
                S = fmaf(S, a16, E);
            }
            if (g == 0)
                cePtr[((size_t)b * NCd + (by * 2 + wm)) * Sd + colBase + j * 16 + fr] = S;
        }
    }

    // ---- epilogue: C/D layout col=lane&15, row=(lane>>4)*4+reg ----
    int m0 = by * 256 + wm * 128 + g * 4;
    int n0 = bx * 256 + wn * 64 + fr;
    if (OBF16) {
        bf16* out = (bf16*)OutV + (size_t)b * oBS;
        #pragma unroll
        for (int i = 0; i < 8; ++i)
            #pragma unroll
            for (int j = 0; j < 4; ++j)
                #pragma unroll
                for (int q = 0; q < 4; ++q)
                    out[(size_t)(m0 + i * 16 + q) * ldOut + n0 + j * 16] = (bf16)acc[i][j][q];
    } else {
        float* out = (float*)OutV + (size_t)b * oBS;
        #pragma unroll
        for (int i = 0; i < 8; ++i)
            #pragma unroll
            for (int j = 0; j < 4; ++j)
                #pragma unroll
                for (int q = 0; q < 4; ++q)
                    out[(size_t)(m0 + i * 16 + q) * ldOut + n0 + j * 16] = acc[i][j][q];
    }
}

// ---- scan pass: carry (redone per block from ce) + full in-place scan, bf16x2
__global__ __launch_bounds__(256) void pass_scan2(bf16* __restrict__ xbuf,
                                                  const float* __restrict__ A_diag,
                                                  const float* __restrict__ ce,
                                                  const float* __restrict__ h0) {
    int gI = blockIdx.x * 256 + threadIdx.x;
    int sp = gI & 255;
    int c = (gI >> 8) & (NCd - 1);
    int b = gI >> 12;
    int s = sp * 2;
    float a0 = A_diag[s], a1 = A_diag[s + 1];
    float acl0 = a0, acl1 = a1;
    #pragma unroll
    for (int i = 0; i < 7; ++i) { acl0 *= acl0; acl1 *= acl1; }   // a^128
    float x0 = h0[s], x1 = h0[s + 1];
    for (int cp = 0; cp < NCd; ++cp) {
        if (cp >= c) break;
        float2 e = *(const float2*)&ce[((size_t)b * NCd + cp) * Sd + s];
        x0 = fmaf(acl0, x0, e.x);
        x1 = fmaf(acl1, x1, e.y);
    }
    bf16* p = xbuf + ((size_t)b * Ld + (size_t)c * CLd) * Sd + s;
    #pragma unroll 4
    for (int j = 0; j < CLd; ++j) {
        bf16x2 v = *(const bf16x2*)&p[(size_t)j * Sd];
        x0 = fmaf(a0, x0, (float)v[0]);
        x1 = fmaf(a1, x1, (float)v[1]);
        bf16x2 o = { (bf16)x0, (bf16)x1 };
        *(bf16x2*)&p[(size_t)j * Sd] = o;
    }
}

extern "C" void kernel_launch(void* const* d_in, const int* in_sizes, int n_in,
                              void* d_out, int out_size, void* d_ws, size_t ws_size,
                              hipStream_t stream) {
    const float* u  = (const float*)d_in[0];
    const float* Au = (const float*)d_in[1];
    const float* Bm = (const float*)d_in[2];
    const float* Cm = (const float*)d_in[3];
    const float* Dm = (const float*)d_in[4];
    const float* h0 = (const float*)d_in[5];
    float* Y = (float*)d_out;

    char* ws = (char*)d_ws;
    bf16* bu = (bf16*)ws;                            // 32 MiB, becomes xs after scan
    bf16* ut = (bf16*)(ws + (32ull << 20));          // 32 MiB
    bf16* Bb = (bf16*)(ws + (64ull << 20));          // 512 KiB each
    bf16* Cb = Bb + 262144;
    bf16* Db = Cb + 262144;
    float* A_diag = (float*)(ws + (64ull << 20) + 3ull * 524288);
    float* ce   = A_diag + 512;                      // 512 KiB
    int*   dfa  = (int*)(ce + (size_t)BZd * NCd * Sd);   // 256 ints, written every call

    prep_all<<<769, 256, 0, stream>>>(Bm, Cm, Dm, Au, Bb, Cb, Db, A_diag, dfa);
    transp_u<<<dim3(Ld / 64, INd / 64, BZd), 256, 0, stream>>>(u, ut);

    // gemm_bu: M=l(2048), N=s(512); A=u_t (batched), B=B_bf (shared); out bu bf16 + ce
    gemm8p<true><<<(Sd / 256) * (Ld / 256) * BZd, 512, 0, stream>>>(
        ut, (size_t)Ld * INd, Bb, 0,
        ut, (size_t)Ld * INd, Bb, 0,
        nullptr,
        A_diag, ce,
        (void*)bu, (size_t)Ld * Sd, Sd,
        Sd / 256, Ld / 256);

    pass_scan2<<<(BZd * NCd * (Sd / 2)) / 256, 256, 0, stream>>>(bu, A_diag, ce, h0);

    // gemm_y: M=o(512), N=l(2048); set0 A=C,B=xs; set1 (iff D!=0) A=D,B=u_t; out Y f32
    gemm8p<false><<<(Ld / 256) * (Od / 256) * BZd, 512, 0, stream>>>(
        Cb, 0, bu, (size_t)Ld * Sd,
        Db, 0, ut, (size_t)Ld * INd,
        dfa,
        A_diag, nullptr,
        (void*)Y, (size_t)Od * Ld, Ld,
        Ld / 256, Od / 256);
}